// Round 7
// baseline (43.357 us; speedup 1.0000x reference)
//
#include <hip/hip_runtime.h>
#include <cstdint>
#include <cstddef>

// HarmonicSynth, single fused kernel (producer/consumer chunk totals, RELAXED
// agent atomics, 384-thread blocks). y[b,n] = sum_h amp[b,n,h]*sin(phases),
// phases = cumsum_n((2pi/48000)*f0[b,n])*(h+1) + phase[b,h]; phase_out =
// last-sample phases mod 2pi. Double scan (numpy f64 ref), f32 harmonic sins.
//
// R4/R5 post-mortems baked in:
//  - RELAXED (not acq/rel) atomics: acquire spin loads emit per-iteration L2
//    invalidates that evict the amp stream (R4: 1.6 TB/s effective).
//  - PF=4 only: PF=8 under the VGPR cap spilled to scratch (R4 VGPR_Count=24).
//  - 384 thr / 6 waves (R6: best occupancy variant).
//  - publish chunk total after ONE butterfly+barrier (not after full scan);
//    per-thread wave-prefix from LDS (no serialized tid0 scan, one less barrier
//    dependency on the critical publish path).
// Deadlock-free: __launch_bounds__(384,6) -> <=84 VGPR -> 4 blocks/CU ->
// 1024 co-resident workgroups >= grid 1000.

#define B   8
#define N   96000
#define H   64
#define CH  768          // samples per chunk (divides N)
#define NCH 125          // N / CH
#define TM  384          // threads (6 waves)
#define NWV 6            // waves per block
#define GM  2            // samples per thread: TM*GM == CH
#define PF  4            // amp float4 prefetches issued before the scan/spin

static_assert(CH * NCH == N, "chunking");
static_assert(TM * GM == CH, "scan layout");
static_assert(NCH <= 128, "predecessor spin uses 2 loads/lane");

static constexpr double TWO_PI_D     = 6.2831853071795864769252867665590057684;
static constexpr double INV_TWO_PI_D = 1.0 / TWO_PI_D;
static constexpr double OMEGA_D      = TWO_PI_D / 48000.0;

__device__ __forceinline__ float wrap2pi_f(double v) {
  double r = v - TWO_PI_D * floor(v * INV_TWO_PI_D);
  return (float)r;   // [0, 2pi); sin periodic so edge rounding harmless
}

__global__ __launch_bounds__(TM, 6) void k_fused(const float* __restrict__ f0,
                                                 const float* __restrict__ amp,
                                                 const float* __restrict__ phase,
                                                 double* __restrict__ csum,
                                                 float* __restrict__ out) {
  const int blk = blockIdx.x;
  const int b = blk / NCH, c = blk - b * NCH;
  const int tid = threadIdx.x;
  const int lane = tid & 63, wv = tid >> 6;
  const size_t base = (size_t)b * N + (size_t)c * CH;

  __shared__ float  s_w[CH];       // per-sample Omega mod 2pi (f32 radians)
  __shared__ double s_wsum[NWV];   // per-wave totals of ts
  __shared__ double s_pre;         // sum of predecessor chunk totals
  __shared__ double s_last;        // full-precision Omega at chunk's last sample

  // --- f0 load (float2) + amp prefetches, all issued up front --------------
  const float2 f0v = reinterpret_cast<const float2*>(f0 + base)[tid];

  const int hq = lane & 15;            // harmonic quad 0..15
  const int sl = lane >> 4;            // sample slot within wave 0..3
  const float4* ampb = reinterpret_cast<const float4*>(amp) + base * (H / 4);
  float4 pf[PF];
#pragma unroll
  for (int j = 0; j < PF; ++j) {
    const int nl = j * (NWV * 4) + (wv << 2) + sl;
    pf[j] = ampb[(size_t)nl * (H / 4) + hq];
  }

  // --- fast path to publishing this block's chunk total --------------------
  const double l0 = OMEGA_D * (double)f0v.x;
  const double l1 = OMEGA_D * (double)f0v.y;
  const double ts = l0 + l1;

  double s = ts;                       // wave butterfly total
  for (int off = 32; off > 0; off >>= 1) s += __shfl_xor(s, off);
  if (lane == 0) s_wsum[wv] = s;
  __syncthreads();                     // barrier 1: s_wsum visible
  if (tid == 0) {
    double total = 0.0;
#pragma unroll
    for (int w = 0; w < NWV; ++w) total += s_wsum[w];
    // RELAXED publish: value is the payload; >= ~8.0 so 0.0 == "not yet"
    __hip_atomic_store(&csum[blk], total, __ATOMIC_RELAXED,
                       __HIP_MEMORY_SCOPE_AGENT);
  }

  // --- wave-inclusive scan + per-thread wave prefix (no serialized scan) ---
  double x = ts;
#pragma unroll
  for (int off = 1; off < 64; off <<= 1) {
    double y = __shfl_up(x, off);
    if (lane >= off) x += y;
  }
  double wavepre = 0.0;
#pragma unroll
  for (int w = 0; w < NWV - 1; ++w) if (w < wv) wavepre += s_wsum[w];

  // --- wave 0: spin until <=124 same-batch predecessors published ----------
  if (wv == 0) {
    const double* cs = csum + b * NCH;
    const bool need0 = (lane < c);
    const bool need1 = (lane + 64 < c);
    double v0 = 0.0, v1 = 0.0;
    for (;;) {
      if (need0 && v0 == 0.0)
        v0 = __hip_atomic_load(&cs[lane], __ATOMIC_RELAXED,
                               __HIP_MEMORY_SCOPE_AGENT);
      if (need1 && v1 == 0.0)
        v1 = __hip_atomic_load(&cs[lane + 64], __ATOMIC_RELAXED,
                               __HIP_MEMORY_SCOPE_AGENT);
      const int done = ((!need0) | (v0 != 0.0)) & ((!need1) | (v1 != 0.0));
      if (__all(done)) break;
      __builtin_amdgcn_s_sleep(2);
    }
    double pre = v0 + v1;
    for (int off = 32; off > 0; off >>= 1) pre += __shfl_xor(pre, off);
    if (lane == 0) s_pre = pre;
  }
  __syncthreads();                     // barrier 2: s_pre ready

  const double run = s_pre + wavepre + (x - ts);   // exclusive prefix
  const double o0 = run + l0;
  const double o1 = o0 + l1;
  s_w[tid * GM + 0] = wrap2pi_f(o0);
  s_w[tid * GM + 1] = wrap2pi_f(o1);
  if (tid == TM - 1) s_last = o1;
  __syncthreads();                     // barrier 3: s_w ready

  // --- synthesis: wave = 4 samples x (16 lanes x 4 harmonics); 6 waves -----
  const float m0 = (float)(hq * 4 + 1), m1 = (float)(hq * 4 + 2);
  const float m2 = (float)(hq * 4 + 3), m3 = (float)(hq * 4 + 4);
  const float* phb = phase + b * H;
  const float p0 = phb[hq * 4 + 0], p1 = phb[hq * 4 + 1];
  const float p2 = phb[hq * 4 + 2], p3 = phb[hq * 4 + 3];
  float* yb = out + base;

#pragma unroll
  for (int j = 0; j < PF; ++j) {
    const int nl = j * (NWV * 4) + (wv << 2) + sl;
    const float w = s_w[nl];
    const float4 a4 = pf[j];
    float acc;
    acc  = a4.x * __sinf(fmaf(w, m0, p0));
    acc += a4.y * __sinf(fmaf(w, m1, p1));
    acc += a4.z * __sinf(fmaf(w, m2, p2));
    acc += a4.w * __sinf(fmaf(w, m3, p3));
    acc += __shfl_xor(acc, 1);
    acc += __shfl_xor(acc, 2);
    acc += __shfl_xor(acc, 4);
    acc += __shfl_xor(acc, 8);
    if (hq == 0) yb[nl] = acc;
  }

#pragma unroll 4
  for (int i0 = PF * (NWV * 4); i0 < CH; i0 += NWV * 4) {
    const int nl = i0 + (wv << 2) + sl;
    const float w = s_w[nl];
    const float4 a4 = ampb[(size_t)nl * (H / 4) + hq];
    float acc;
    acc  = a4.x * __sinf(fmaf(w, m0, p0));
    acc += a4.y * __sinf(fmaf(w, m1, p1));
    acc += a4.z * __sinf(fmaf(w, m2, p2));
    acc += a4.w * __sinf(fmaf(w, m3, p3));
    acc += __shfl_xor(acc, 1);
    acc += __shfl_xor(acc, 2);
    acc += __shfl_xor(acc, 4);
    acc += __shfl_xor(acc, 8);
    if (hq == 0) yb[nl] = acc;
  }

  // --- phase_out from the last chunk (double remainder) --------------------
  if (c == NCH - 1 && tid < H) {
    const double arg = s_last * (double)(tid + 1) + (double)phase[b * H + tid];
    double r = arg - TWO_PI_D * floor(arg * INV_TWO_PI_D);
    if (r < 0.0) r += TWO_PI_D;
    if (r >= TWO_PI_D) r -= TWO_PI_D;
    out[(size_t)B * N + b * H + tid] = (float)r;
  }
}

extern "C" void kernel_launch(void* const* d_in, const int* in_sizes, int n_in,
                              void* d_out, int out_size, void* d_ws, size_t ws_size,
                              hipStream_t stream) {
  const float* f0    = (const float*)d_in[0];   // (B, N)
  const float* amp   = (const float*)d_in[1];   // (B, N, H)
  const float* phase = (const float*)d_in[2];   // (B, H)
  float* out = (float*)d_out;                   // y (B*N) ++ phase_out (B*H)
  double* csum = (double*)d_ws;                 // B*NCH doubles = 8000 B

  // 0.0 == "not yet published" (ws may hold 0xAA poison or stale values)
  hipMemsetAsync(d_ws, 0, (size_t)B * NCH * sizeof(double), stream);
  k_fused<<<B * NCH, TM, 0, stream>>>(f0, amp, phase, csum, out);
}

// Round 9
// 41.201 us; speedup vs baseline: 1.0523x; 1.0523x over previous
//
#include <hip/hip_runtime.h>
#include <cstdint>
#include <cstddef>

// HarmonicSynth, two-kernel structure (R6 skeleton — both fusion variants
// measured slower: R5 45.0, R7 43.4 vs R6 39.2).
// y[b,n] = sum_h amp[b,n,h]*sin(Omega[b,n]*(h+1)+phase[b,h]);
// Omega = inclusive prefix of (2pi/48000)*f0; phase_out = Omega[N-1] harmonics
// mod 2pi. Double scan (numpy f64 ref), f32 harmonic sins (arg < 403 rad).
//
// R7 trims: (1) k1 = wave-per-chunk float4 butterfly (no LDS/barrier);
// (2) k_main prologue 2 barriers, per-thread wave-prefix from LDS (no
// serialized tid0 scan); (3) nontemporal amp loads via native clang vector
// type (ext_vector_type(4)) — __builtin_nontemporal_load rejects the
// HIP_vector_type struct (R8 compile fail).

#define B   8
#define N   96000
#define H   64
#define CH  768          // samples per chunk (divides N)
#define NCH 125          // N / CH
#define TM  384          // k_main threads (6 waves)
#define NWV 6            // waves per k_main block
#define GM  2            // samples per k_main thread: TM*GM == CH
#define PF  4            // amp float4 prefetches issued before the scan

static_assert(CH * NCH == N, "chunking");
static_assert(TM * GM == CH, "main scan layout");
static_assert(NCH <= 128, "predecessor sum uses 2 loads/lane");

typedef float vf4 __attribute__((ext_vector_type(4)));   // native vector for NT loads

static constexpr double TWO_PI_D     = 6.2831853071795864769252867665590057684;
static constexpr double INV_TWO_PI_D = 1.0 / TWO_PI_D;
static constexpr double OMEGA_D      = TWO_PI_D / 48000.0;

__device__ __forceinline__ float wrap2pi_f(double v) {
  double r = v - TWO_PI_D * floor(v * INV_TWO_PI_D);
  return (float)r;   // [0, 2pi); sin periodic so edge rounding harmless
}

// ---- Kernel 1: per-chunk sums of omega, one wave per chunk ----------------
// 250 blocks x 4 waves; wave w owns chunk blockIdx.x*4+w. Each lane: 3 vf4
// loads (192 float4 per 768-sample chunk / 64 lanes), double sum, butterfly.
__global__ __launch_bounds__(256) void k_chunk_sums(const float* __restrict__ f0,
                                                    double* __restrict__ csum) {
  const int chunk = (blockIdx.x << 2) + (threadIdx.x >> 6);   // 0..999
  const int lane = threadIdx.x & 63;
  const int b = chunk / NCH, c = chunk - b * NCH;
  const vf4* p = reinterpret_cast<const vf4*>(f0 + (size_t)b * N + (size_t)c * CH);

  double s = 0.0;
#pragma unroll
  for (int j = 0; j < 3; ++j) {
    const vf4 v = p[lane + j * 64];
    s += ((double)v.x + (double)v.y) + ((double)v.z + (double)v.w);
  }
  for (int off = 32; off > 0; off >>= 1) s += __shfl_xor(s, off);
  if (lane == 0) csum[chunk] = OMEGA_D * s;
}

// ---- Kernel 2: main — predecessor sum + in-block scan + synthesis ---------
__global__ __launch_bounds__(TM, 6) void k_main(const float* __restrict__ f0,
                                                const float* __restrict__ amp,
                                                const float* __restrict__ phase,
                                                const double* __restrict__ csum,
                                                float* __restrict__ out) {
  const int blk = blockIdx.x;
  const int b = blk / NCH, c = blk - b * NCH;
  const int tid = threadIdx.x;
  const int lane = tid & 63, wv = tid >> 6;
  const size_t base = (size_t)b * N + (size_t)c * CH;

  __shared__ float  s_w[CH];       // per-sample Omega mod 2pi (f32 radians)
  __shared__ double s_wsum[NWV];   // per-wave totals
  __shared__ double s_pre;         // sum of predecessor chunk totals
  __shared__ double s_last;        // full-precision Omega at chunk's last sample

  // --- f0 load (float2) + amp prefetches, issued up front ------------------
  const float2 f0v = reinterpret_cast<const float2*>(f0 + base)[tid];

  const int hq = lane & 15;            // harmonic quad 0..15
  const int sl = lane >> 4;            // sample slot within wave 0..3
  const vf4* ampb = reinterpret_cast<const vf4*>(amp) + base * (H / 4);
  vf4 pf[PF];
#pragma unroll
  for (int j = 0; j < PF; ++j) {
    const int nl = j * (NWV * 4) + (wv << 2) + sl;
    pf[j] = __builtin_nontemporal_load(&ampb[(size_t)nl * (H / 4) + hq]);
  }

  // --- per-wave butterfly total; wave 0 also fetches predecessor prefix ----
  const double l0 = OMEGA_D * (double)f0v.x;
  const double l1 = OMEGA_D * (double)f0v.y;
  const double ts = l0 + l1;

  double s = ts;
  for (int off = 32; off > 0; off >>= 1) s += __shfl_xor(s, off);
  if (lane == 0) s_wsum[wv] = s;

  if (wv == 0) {
    double pre = 0.0;
    if (lane < c)      pre  = csum[b * NCH + lane];
    if (lane + 64 < c) pre += csum[b * NCH + lane + 64];
    for (int off = 32; off > 0; off >>= 1) pre += __shfl_xor(pre, off);
    if (lane == 0) s_pre = pre;
  }

  // wave-inclusive scan (register-only, overlaps the barrier wait)
  double x = ts;
#pragma unroll
  for (int off = 1; off < 64; off <<= 1) {
    double y = __shfl_up(x, off);
    if (lane >= off) x += y;
  }
  __syncthreads();                     // barrier 1: s_wsum + s_pre visible

  double wavepre = s_pre;
#pragma unroll
  for (int w = 0; w < NWV - 1; ++w) if (w < wv) wavepre += s_wsum[w];

  const double run = wavepre + (x - ts);   // exclusive prefix for this thread
  const double o0 = run + l0;
  const double o1 = o0 + l1;
  s_w[tid * GM + 0] = wrap2pi_f(o0);
  s_w[tid * GM + 1] = wrap2pi_f(o1);
  if (tid == TM - 1) s_last = o1;
  __syncthreads();                     // barrier 2: s_w ready

  // --- synthesis: wave = 4 samples x (16 lanes x 4 harmonics); 6 waves -----
  const float m0 = (float)(hq * 4 + 1), m1 = (float)(hq * 4 + 2);
  const float m2 = (float)(hq * 4 + 3), m3 = (float)(hq * 4 + 4);
  const float* phb = phase + b * H;
  const float p0 = phb[hq * 4 + 0], p1 = phb[hq * 4 + 1];
  const float p2 = phb[hq * 4 + 2], p3 = phb[hq * 4 + 3];
  float* yb = out + base;

#pragma unroll
  for (int j = 0; j < PF; ++j) {
    const int nl = j * (NWV * 4) + (wv << 2) + sl;
    const float w = s_w[nl];
    const vf4 a4 = pf[j];
    float acc;
    acc  = a4.x * __sinf(fmaf(w, m0, p0));
    acc += a4.y * __sinf(fmaf(w, m1, p1));
    acc += a4.z * __sinf(fmaf(w, m2, p2));
    acc += a4.w * __sinf(fmaf(w, m3, p3));
    acc += __shfl_xor(acc, 1);
    acc += __shfl_xor(acc, 2);
    acc += __shfl_xor(acc, 4);
    acc += __shfl_xor(acc, 8);
    if (hq == 0) yb[nl] = acc;
  }

#pragma unroll 4
  for (int i0 = PF * (NWV * 4); i0 < CH; i0 += NWV * 4) {
    const int nl = i0 + (wv << 2) + sl;
    const float w = s_w[nl];
    const vf4 a4 = __builtin_nontemporal_load(&ampb[(size_t)nl * (H / 4) + hq]);
    float acc;
    acc  = a4.x * __sinf(fmaf(w, m0, p0));
    acc += a4.y * __sinf(fmaf(w, m1, p1));
    acc += a4.z * __sinf(fmaf(w, m2, p2));
    acc += a4.w * __sinf(fmaf(w, m3, p3));
    acc += __shfl_xor(acc, 1);
    acc += __shfl_xor(acc, 2);
    acc += __shfl_xor(acc, 4);
    acc += __shfl_xor(acc, 8);
    if (hq == 0) yb[nl] = acc;
  }

  // --- phase_out from the last chunk (double remainder) --------------------
  if (c == NCH - 1 && tid < H) {
    const double arg = s_last * (double)(tid + 1) + (double)phase[b * H + tid];
    double r = arg - TWO_PI_D * floor(arg * INV_TWO_PI_D);
    if (r < 0.0) r += TWO_PI_D;
    if (r >= TWO_PI_D) r -= TWO_PI_D;
    out[(size_t)B * N + b * H + tid] = (float)r;
  }
}

extern "C" void kernel_launch(void* const* d_in, const int* in_sizes, int n_in,
                              void* d_out, int out_size, void* d_ws, size_t ws_size,
                              hipStream_t stream) {
  const float* f0    = (const float*)d_in[0];   // (B, N)
  const float* amp   = (const float*)d_in[1];   // (B, N, H)
  const float* phase = (const float*)d_in[2];   // (B, H)
  float* out = (float*)d_out;                   // y (B*N) ++ phase_out (B*H)
  double* csum = (double*)d_ws;                 // B*NCH doubles = 8000 B

  k_chunk_sums<<<(B * NCH) / 4, 256, 0, stream>>>(f0, csum);
  k_main<<<B * NCH, TM, 0, stream>>>(f0, amp, phase, csum, out);
}

// Round 10
// 40.058 us; speedup vs baseline: 1.0823x; 1.0285x over previous
//
#include <hip/hip_runtime.h>
#include <cstdint>
#include <cstddef>

// HarmonicSynth, two-kernel structure (R6 skeleton — fusion variants measured
// slower: R5 45.0, R7 43.4 vs R6 39.2).
// y[b,n] = sum_h amp[b,n,h]*sin(Omega[b,n]*(h+1)+phase[b,h]);
// Omega = inclusive prefix of (2pi/48000)*f0; phase_out = Omega[N-1] harmonics
// mod 2pi. Double scan (numpy f64 ref), f32 harmonic sins (arg < 403 rad).
//
// R9 post-mortem: NT loads regressed (timed replays are L3-resident; evict-
// first hints discard that residency on 197MB of traffic). This round: plain
// loads again (single A/B revert); keep wave-per-chunk k1 + 2-barrier prologue.

#define B   8
#define N   96000
#define H   64
#define CH  768          // samples per chunk (divides N)
#define NCH 125          // N / CH
#define TM  384          // k_main threads (6 waves)
#define NWV 6            // waves per k_main block
#define GM  2            // samples per k_main thread: TM*GM == CH
#define PF  4            // amp float4 prefetches issued before the scan

static_assert(CH * NCH == N, "chunking");
static_assert(TM * GM == CH, "main scan layout");
static_assert(NCH <= 128, "predecessor sum uses 2 loads/lane");

typedef float vf4 __attribute__((ext_vector_type(4)));

static constexpr double TWO_PI_D     = 6.2831853071795864769252867665590057684;
static constexpr double INV_TWO_PI_D = 1.0 / TWO_PI_D;
static constexpr double OMEGA_D      = TWO_PI_D / 48000.0;

__device__ __forceinline__ float wrap2pi_f(double v) {
  double r = v - TWO_PI_D * floor(v * INV_TWO_PI_D);
  return (float)r;   // [0, 2pi); sin periodic so edge rounding harmless
}

// ---- Kernel 1: per-chunk sums of omega, one wave per chunk ----------------
// 250 blocks x 4 waves; wave w owns chunk blockIdx.x*4+w. Each lane: 3 vf4
// loads, double sum, 6-level butterfly. No LDS, no barrier.
__global__ __launch_bounds__(256) void k_chunk_sums(const float* __restrict__ f0,
                                                    double* __restrict__ csum) {
  const int chunk = (blockIdx.x << 2) + (threadIdx.x >> 6);   // 0..999
  const int lane = threadIdx.x & 63;
  const int b = chunk / NCH, c = chunk - b * NCH;
  const vf4* p = reinterpret_cast<const vf4*>(f0 + (size_t)b * N + (size_t)c * CH);

  double s = 0.0;
#pragma unroll
  for (int j = 0; j < 3; ++j) {
    const vf4 v = p[lane + j * 64];
    s += ((double)v.x + (double)v.y) + ((double)v.z + (double)v.w);
  }
  for (int off = 32; off > 0; off >>= 1) s += __shfl_xor(s, off);
  if (lane == 0) csum[chunk] = OMEGA_D * s;
}

// ---- Kernel 2: main — predecessor sum + in-block scan + synthesis ---------
__global__ __launch_bounds__(TM, 6) void k_main(const float* __restrict__ f0,
                                                const float* __restrict__ amp,
                                                const float* __restrict__ phase,
                                                const double* __restrict__ csum,
                                                float* __restrict__ out) {
  const int blk = blockIdx.x;
  const int b = blk / NCH, c = blk - b * NCH;
  const int tid = threadIdx.x;
  const int lane = tid & 63, wv = tid >> 6;
  const size_t base = (size_t)b * N + (size_t)c * CH;

  __shared__ float  s_w[CH];       // per-sample Omega mod 2pi (f32 radians)
  __shared__ double s_wsum[NWV];   // per-wave totals
  __shared__ double s_pre;         // sum of predecessor chunk totals
  __shared__ double s_last;        // full-precision Omega at chunk's last sample

  // --- f0 load (float2) + amp prefetches, issued up front ------------------
  const float2 f0v = reinterpret_cast<const float2*>(f0 + base)[tid];

  const int hq = lane & 15;            // harmonic quad 0..15
  const int sl = lane >> 4;            // sample slot within wave 0..3
  const vf4* ampb = reinterpret_cast<const vf4*>(amp) + base * (H / 4);
  vf4 pf[PF];
#pragma unroll
  for (int j = 0; j < PF; ++j) {
    const int nl = j * (NWV * 4) + (wv << 2) + sl;
    pf[j] = ampb[(size_t)nl * (H / 4) + hq];
  }

  // --- per-wave butterfly total; wave 0 also fetches predecessor prefix ----
  const double l0 = OMEGA_D * (double)f0v.x;
  const double l1 = OMEGA_D * (double)f0v.y;
  const double ts = l0 + l1;

  double s = ts;
  for (int off = 32; off > 0; off >>= 1) s += __shfl_xor(s, off);
  if (lane == 0) s_wsum[wv] = s;

  if (wv == 0) {
    double pre = 0.0;
    if (lane < c)      pre  = csum[b * NCH + lane];
    if (lane + 64 < c) pre += csum[b * NCH + lane + 64];
    for (int off = 32; off > 0; off >>= 1) pre += __shfl_xor(pre, off);
    if (lane == 0) s_pre = pre;
  }

  // wave-inclusive scan (register-only, overlaps the barrier wait)
  double x = ts;
#pragma unroll
  for (int off = 1; off < 64; off <<= 1) {
    double y = __shfl_up(x, off);
    if (lane >= off) x += y;
  }
  __syncthreads();                     // barrier 1: s_wsum + s_pre visible

  double wavepre = s_pre;
#pragma unroll
  for (int w = 0; w < NWV - 1; ++w) if (w < wv) wavepre += s_wsum[w];

  const double run = wavepre + (x - ts);   // exclusive prefix for this thread
  const double o0 = run + l0;
  const double o1 = o0 + l1;
  s_w[tid * GM + 0] = wrap2pi_f(o0);
  s_w[tid * GM + 1] = wrap2pi_f(o1);
  if (tid == TM - 1) s_last = o1;
  __syncthreads();                     // barrier 2: s_w ready

  // --- synthesis: wave = 4 samples x (16 lanes x 4 harmonics); 6 waves -----
  const float m0 = (float)(hq * 4 + 1), m1 = (float)(hq * 4 + 2);
  const float m2 = (float)(hq * 4 + 3), m3 = (float)(hq * 4 + 4);
  const float* phb = phase + b * H;
  const float p0 = phb[hq * 4 + 0], p1 = phb[hq * 4 + 1];
  const float p2 = phb[hq * 4 + 2], p3 = phb[hq * 4 + 3];
  float* yb = out + base;

#pragma unroll
  for (int j = 0; j < PF; ++j) {
    const int nl = j * (NWV * 4) + (wv << 2) + sl;
    const float w = s_w[nl];
    const vf4 a4 = pf[j];
    float acc;
    acc  = a4.x * __sinf(fmaf(w, m0, p0));
    acc += a4.y * __sinf(fmaf(w, m1, p1));
    acc += a4.z * __sinf(fmaf(w, m2, p2));
    acc += a4.w * __sinf(fmaf(w, m3, p3));
    acc += __shfl_xor(acc, 1);
    acc += __shfl_xor(acc, 2);
    acc += __shfl_xor(acc, 4);
    acc += __shfl_xor(acc, 8);
    if (hq == 0) yb[nl] = acc;
  }

#pragma unroll 4
  for (int i0 = PF * (NWV * 4); i0 < CH; i0 += NWV * 4) {
    const int nl = i0 + (wv << 2) + sl;
    const float w = s_w[nl];
    const vf4 a4 = ampb[(size_t)nl * (H / 4) + hq];
    float acc;
    acc  = a4.x * __sinf(fmaf(w, m0, p0));
    acc += a4.y * __sinf(fmaf(w, m1, p1));
    acc += a4.z * __sinf(fmaf(w, m2, p2));
    acc += a4.w * __sinf(fmaf(w, m3, p3));
    acc += __shfl_xor(acc, 1);
    acc += __shfl_xor(acc, 2);
    acc += __shfl_xor(acc, 4);
    acc += __shfl_xor(acc, 8);
    if (hq == 0) yb[nl] = acc;
  }

  // --- phase_out from the last chunk (double remainder) --------------------
  if (c == NCH - 1 && tid < H) {
    const double arg = s_last * (double)(tid + 1) + (double)phase[b * H + tid];
    double r = arg - TWO_PI_D * floor(arg * INV_TWO_PI_D);
    if (r < 0.0) r += TWO_PI_D;
    if (r >= TWO_PI_D) r -= TWO_PI_D;
    out[(size_t)B * N + b * H + tid] = (float)r;
  }
}

extern "C" void kernel_launch(void* const* d_in, const int* in_sizes, int n_in,
                              void* d_out, int out_size, void* d_ws, size_t ws_size,
                              hipStream_t stream) {
  const float* f0    = (const float*)d_in[0];   // (B, N)
  const float* amp   = (const float*)d_in[1];   // (B, N, H)
  const float* phase = (const float*)d_in[2];   // (B, H)
  float* out = (float*)d_out;                   // y (B*N) ++ phase_out (B*H)
  double* csum = (double*)d_ws;                 // B*NCH doubles = 8000 B

  k_chunk_sums<<<(B * NCH) / 4, 256, 0, stream>>>(f0, csum);
  k_main<<<B * NCH, TM, 0, stream>>>(f0, amp, phase, csum, out);
}

// Round 11
// 39.487 us; speedup vs baseline: 1.0980x; 1.0145x over previous
//
#include <hip/hip_runtime.h>
#include <cstdint>
#include <cstddef>

// HarmonicSynth, two-kernel structure (fusion measured slower twice: R5 45.0,
// R7 43.4 vs R6 39.2). y[b,n] = sum_h amp[b,n,h]*sin(Omega[b,n]*(h+1)+phase[b,h]);
// Omega = inclusive prefix of (2pi/48000)*f0; phase_out = Omega[N-1] harmonics
// mod 2pi. Double scan (numpy f64 ref), f32 harmonic sins (arg < 403 rad).
//
// R10 post-mortem: NT loads were the R9 regression (timed replays L3-resident;
// evict-first discards that residency). This round, single change vs R10:
// PF 4->8 and steady-loop unroll 4->8 (deeper VMEM pipeline; ~900cy HBM latency
// vs ~300cy of compute per 4-deep group). VGPR headroom ample (<=341 for
// 24 waves/CU; pf[8]=32 regs, all compile-time indexed).

#define B   8
#define N   96000
#define H   64
#define CH  768          // samples per chunk (divides N)
#define NCH 125          // N / CH
#define TM  384          // k_main threads (6 waves)
#define NWV 6            // waves per k_main block
#define GM  2            // samples per k_main thread: TM*GM == CH
#define PF  8            // amp float4 prefetches issued before the scan

static_assert(CH * NCH == N, "chunking");
static_assert(TM * GM == CH, "main scan layout");
static_assert(NCH <= 128, "predecessor sum uses 2 loads/lane");

typedef float vf4 __attribute__((ext_vector_type(4)));

static constexpr double TWO_PI_D     = 6.2831853071795864769252867665590057684;
static constexpr double INV_TWO_PI_D = 1.0 / TWO_PI_D;
static constexpr double OMEGA_D      = TWO_PI_D / 48000.0;

__device__ __forceinline__ float wrap2pi_f(double v) {
  double r = v - TWO_PI_D * floor(v * INV_TWO_PI_D);
  return (float)r;   // [0, 2pi); sin periodic so edge rounding harmless
}

// ---- Kernel 1: per-chunk sums of omega, one wave per chunk ----------------
__global__ __launch_bounds__(256) void k_chunk_sums(const float* __restrict__ f0,
                                                    double* __restrict__ csum) {
  const int chunk = (blockIdx.x << 2) + (threadIdx.x >> 6);   // 0..999
  const int lane = threadIdx.x & 63;
  const int b = chunk / NCH, c = chunk - b * NCH;
  const vf4* p = reinterpret_cast<const vf4*>(f0 + (size_t)b * N + (size_t)c * CH);

  double s = 0.0;
#pragma unroll
  for (int j = 0; j < 3; ++j) {
    const vf4 v = p[lane + j * 64];
    s += ((double)v.x + (double)v.y) + ((double)v.z + (double)v.w);
  }
  for (int off = 32; off > 0; off >>= 1) s += __shfl_xor(s, off);
  if (lane == 0) csum[chunk] = OMEGA_D * s;
}

// ---- Kernel 2: main — predecessor sum + in-block scan + synthesis ---------
__global__ __launch_bounds__(TM, 6) void k_main(const float* __restrict__ f0,
                                                const float* __restrict__ amp,
                                                const float* __restrict__ phase,
                                                const double* __restrict__ csum,
                                                float* __restrict__ out) {
  const int blk = blockIdx.x;
  const int b = blk / NCH, c = blk - b * NCH;
  const int tid = threadIdx.x;
  const int lane = tid & 63, wv = tid >> 6;
  const size_t base = (size_t)b * N + (size_t)c * CH;

  __shared__ float  s_w[CH];       // per-sample Omega mod 2pi (f32 radians)
  __shared__ double s_wsum[NWV];   // per-wave totals
  __shared__ double s_pre;         // sum of predecessor chunk totals
  __shared__ double s_last;        // full-precision Omega at chunk's last sample

  // --- f0 load (float2) + amp prefetches, issued up front ------------------
  const float2 f0v = reinterpret_cast<const float2*>(f0 + base)[tid];

  const int hq = lane & 15;            // harmonic quad 0..15
  const int sl = lane >> 4;            // sample slot within wave 0..3
  const vf4* ampb = reinterpret_cast<const vf4*>(amp) + base * (H / 4);
  vf4 pf[PF];
#pragma unroll
  for (int j = 0; j < PF; ++j) {
    const int nl = j * (NWV * 4) + (wv << 2) + sl;
    pf[j] = ampb[(size_t)nl * (H / 4) + hq];
  }

  // --- per-wave butterfly total; wave 0 also fetches predecessor prefix ----
  const double l0 = OMEGA_D * (double)f0v.x;
  const double l1 = OMEGA_D * (double)f0v.y;
  const double ts = l0 + l1;

  double s = ts;
  for (int off = 32; off > 0; off >>= 1) s += __shfl_xor(s, off);
  if (lane == 0) s_wsum[wv] = s;

  if (wv == 0) {
    double pre = 0.0;
    if (lane < c)      pre  = csum[b * NCH + lane];
    if (lane + 64 < c) pre += csum[b * NCH + lane + 64];
    for (int off = 32; off > 0; off >>= 1) pre += __shfl_xor(pre, off);
    if (lane == 0) s_pre = pre;
  }

  // wave-inclusive scan (register-only, overlaps the barrier wait)
  double x = ts;
#pragma unroll
  for (int off = 1; off < 64; off <<= 1) {
    double y = __shfl_up(x, off);
    if (lane >= off) x += y;
  }
  __syncthreads();                     // barrier 1: s_wsum + s_pre visible

  double wavepre = s_pre;
#pragma unroll
  for (int w = 0; w < NWV - 1; ++w) if (w < wv) wavepre += s_wsum[w];

  const double run = wavepre + (x - ts);   // exclusive prefix for this thread
  const double o0 = run + l0;
  const double o1 = o0 + l1;
  s_w[tid * GM + 0] = wrap2pi_f(o0);
  s_w[tid * GM + 1] = wrap2pi_f(o1);
  if (tid == TM - 1) s_last = o1;
  __syncthreads();                     // barrier 2: s_w ready

  // --- synthesis: wave = 4 samples x (16 lanes x 4 harmonics); 6 waves -----
  const float m0 = (float)(hq * 4 + 1), m1 = (float)(hq * 4 + 2);
  const float m2 = (float)(hq * 4 + 3), m3 = (float)(hq * 4 + 4);
  const float* phb = phase + b * H;
  const float p0 = phb[hq * 4 + 0], p1 = phb[hq * 4 + 1];
  const float p2 = phb[hq * 4 + 2], p3 = phb[hq * 4 + 3];
  float* yb = out + base;

#pragma unroll
  for (int j = 0; j < PF; ++j) {
    const int nl = j * (NWV * 4) + (wv << 2) + sl;
    const float w = s_w[nl];
    const vf4 a4 = pf[j];
    float acc;
    acc  = a4.x * __sinf(fmaf(w, m0, p0));
    acc += a4.y * __sinf(fmaf(w, m1, p1));
    acc += a4.z * __sinf(fmaf(w, m2, p2));
    acc += a4.w * __sinf(fmaf(w, m3, p3));
    acc += __shfl_xor(acc, 1);
    acc += __shfl_xor(acc, 2);
    acc += __shfl_xor(acc, 4);
    acc += __shfl_xor(acc, 8);
    if (hq == 0) yb[nl] = acc;
  }

#pragma unroll 8
  for (int i0 = PF * (NWV * 4); i0 < CH; i0 += NWV * 4) {
    const int nl = i0 + (wv << 2) + sl;
    const float w = s_w[nl];
    const vf4 a4 = ampb[(size_t)nl * (H / 4) + hq];
    float acc;
    acc  = a4.x * __sinf(fmaf(w, m0, p0));
    acc += a4.y * __sinf(fmaf(w, m1, p1));
    acc += a4.z * __sinf(fmaf(w, m2, p2));
    acc += a4.w * __sinf(fmaf(w, m3, p3));
    acc += __shfl_xor(acc, 1);
    acc += __shfl_xor(acc, 2);
    acc += __shfl_xor(acc, 4);
    acc += __shfl_xor(acc, 8);
    if (hq == 0) yb[nl] = acc;
  }

  // --- phase_out from the last chunk (double remainder) --------------------
  if (c == NCH - 1 && tid < H) {
    const double arg = s_last * (double)(tid + 1) + (double)phase[b * H + tid];
    double r = arg - TWO_PI_D * floor(arg * INV_TWO_PI_D);
    if (r < 0.0) r += TWO_PI_D;
    if (r >= TWO_PI_D) r -= TWO_PI_D;
    out[(size_t)B * N + b * H + tid] = (float)r;
  }
}

extern "C" void kernel_launch(void* const* d_in, const int* in_sizes, int n_in,
                              void* d_out, int out_size, void* d_ws, size_t ws_size,
                              hipStream_t stream) {
  const float* f0    = (const float*)d_in[0];   // (B, N)
  const float* amp   = (const float*)d_in[1];   // (B, N, H)
  const float* phase = (const float*)d_in[2];   // (B, H)
  float* out = (float*)d_out;                   // y (B*N) ++ phase_out (B*H)
  double* csum = (double*)d_ws;                 // B*NCH doubles = 8000 B

  k_chunk_sums<<<(B * NCH) / 4, 256, 0, stream>>>(f0, csum);
  k_main<<<B * NCH, TM, 0, stream>>>(f0, amp, phase, csum, out);
}